// Round 7
// baseline (1115.584 us; speedup 1.0000x reference)
//
#include <hip/hip_runtime.h>

#define S_TOK 8192
#define C_DIM 1024
#define E_NUM 8
#define HID_DIM 4096

typedef unsigned short u16;
typedef __bf16 bf16x8 __attribute__((ext_vector_type(8)));
typedef float f32x4 __attribute__((ext_vector_type(4)));

__device__ __forceinline__ u16 f2bf(float f){
  union { float f; unsigned u; } v; v.f = f;
  unsigned r = v.u + 0x7fffu + ((v.u >> 16) & 1u);
  return (u16)(r >> 16);
}
__device__ __forceinline__ float bf2f(u16 b){
  union { unsigned u; float f; } v; v.u = ((unsigned)b) << 16; return v.f;
}

__device__ __forceinline__ void async_copy16(const void* g, void* l){
  __builtin_amdgcn_global_load_lds((const __attribute__((address_space(1))) void*)g,
                                   (__attribute__((address_space(3))) void*)l, 16, 0, 0);
}

#define WAIT_VM(N) asm volatile("s_waitcnt vmcnt(" #N ")" ::: "memory")
#define BAR_ENTER() do{ asm volatile("" ::: "memory"); __builtin_amdgcn_s_barrier(); \
                        __builtin_amdgcn_sched_barrier(0); }while(0)
#define BAR_EXIT()  do{ asm volatile("" ::: "memory"); __builtin_amdgcn_s_barrier(); }while(0)

// ---------------- gate: logits -> softmax -> top2 -> stats; also emits xb (bf16 x) ----------------
__global__ __launch_bounds__(256) void gate_kernel(
    const float* __restrict__ x, const float* __restrict__ wg_w, const float* __restrict__ wg_b,
    u16* __restrict__ xb,
    int* __restrict__ top_idx, float* __restrict__ top_val,
    float* __restrict__ imp_sum, int* __restrict__ cnt_top1, int* __restrict__ counts)
{
  __shared__ float s_imp[E_NUM];
  __shared__ int   s_c1[E_NUM], s_cnt[E_NUM];
  if (threadIdx.x < E_NUM){ s_imp[threadIdx.x]=0.f; s_c1[threadIdx.x]=0; s_cnt[threadIdx.x]=0; }
  __syncthreads();

  int wid = threadIdx.x >> 6, lane = threadIdx.x & 63;
  int t = blockIdx.x * 4 + wid;
  const float4* xr4 = (const float4*)(x + (size_t)t * C_DIM);
  u16* xbr = xb + (size_t)t * C_DIM;
  float acc[E_NUM];
  #pragma unroll
  for (int e=0;e<E_NUM;e++) acc[e]=0.f;
  #pragma unroll
  for (int c4 = 0; c4 < C_DIM/4/64; c4++){
    int c = (c4*64 + lane);
    float4 xv = xr4[c];
    ushort4 o = make_ushort4(f2bf(xv.x), f2bf(xv.y), f2bf(xv.z), f2bf(xv.w));
    *(ushort4*)&xbr[c*4] = o;
    const float* wr = wg_w + (size_t)c * 4 * E_NUM;
    #pragma unroll
    for (int e=0;e<E_NUM;e++)
      acc[e] += xv.x*wr[e] + xv.y*wr[E_NUM+e] + xv.z*wr[2*E_NUM+e] + xv.w*wr[3*E_NUM+e];
  }
  #pragma unroll
  for (int e=0;e<E_NUM;e++){
    float v = acc[e];
    #pragma unroll
    for (int off=32; off>0; off>>=1) v += __shfl_xor(v, off, 64);
    acc[e] = v + wg_b[e];
  }
  float mx = acc[0];
  #pragma unroll
  for (int e=1;e<E_NUM;e++) mx = fmaxf(mx, acc[e]);
  float sum = 0.f;
  #pragma unroll
  for (int e=0;e<E_NUM;e++){ acc[e] = __expf(acc[e]-mx); sum += acc[e]; }
  float inv = 1.f/sum;
  #pragma unroll
  for (int e=0;e<E_NUM;e++) acc[e] *= inv;
  int i1=0; float v1=acc[0];
  #pragma unroll
  for (int e=1;e<E_NUM;e++) if (acc[e] > v1){ v1=acc[e]; i1=e; }
  int i2=-1; float v2=-1.f;
  #pragma unroll
  for (int e=0;e<E_NUM;e++) if (e!=i1 && acc[e] > v2){ v2=acc[e]; i2=e; }

  if (lane==0){
    top_idx[t*2+0]=i1; top_idx[t*2+1]=i2;
    top_val[t*2+0]=v1; top_val[t*2+1]=v2;
    #pragma unroll
    for (int e=0;e<E_NUM;e++) atomicAdd(&s_imp[e], acc[e]);
    atomicAdd(&s_c1[i1],1);
    atomicAdd(&s_cnt[i1],1); atomicAdd(&s_cnt[i2],1);
  }
  __syncthreads();
  if (threadIdx.x < E_NUM){
    atomicAdd(&imp_sum[threadIdx.x], s_imp[threadIdx.x]);
    atomicAdd(&cnt_top1[threadIdx.x], s_c1[threadIdx.x]);
    atomicAdd(&counts[threadIdx.x], s_cnt[threadIdx.x]);
  }
}

// ---------------- scan: offsets, cursors, aux ----------------
__global__ void scan_kernel(const int* __restrict__ counts, int* __restrict__ offsets,
                            int* __restrict__ cursor, const float* __restrict__ imp_sum,
                            const int* __restrict__ cnt_top1, float* __restrict__ aux_out)
{
  if (threadIdx.x==0 && blockIdx.x==0){
    int off=0;
    #pragma unroll
    for (int e=0;e<E_NUM;e++){ offsets[e]=off; cursor[e]=off; off+=counts[e]; }
    float aux=0.f;
    #pragma unroll
    for (int e=0;e<E_NUM;e++)
      aux += (imp_sum[e]/(float)S_TOK) * ((float)cnt_top1[e]/(float)S_TOK);
    aux_out[0] = aux * (float)E_NUM;
  }
}

// ---------------- scatter ----------------
__global__ __launch_bounds__(256) void scatter_kernel(
    const int* __restrict__ top_idx, const float* __restrict__ top_val,
    int* __restrict__ cursor, int* __restrict__ token_list, float* __restrict__ token_w,
    int* __restrict__ pos_of_slot)
{
  int t = blockIdx.x*256 + threadIdx.x;
  #pragma unroll
  for (int k=0;k<2;k++){
    int e = top_idx[t*2+k];
    int pos = atomicAdd(&cursor[e], 1);
    token_list[pos] = t;
    token_w[pos]    = top_val[t*2+k];
    pos_of_slot[t*2+k] = pos;
  }
}

// ---------------- weight transpose fp32 (R x Cc) -> bf16 (Cc x R) ----------------
__global__ __launch_bounds__(256) void transpose_kernel(const float* __restrict__ in, u16* __restrict__ out,
                                                        int R, int Cc)
{
  __shared__ float tile[64][65];
  int e = blockIdx.z;
  const float* src = in  + (size_t)e*R*Cc;
  u16*         dst = out + (size_t)e*R*Cc;
  int c0 = blockIdx.x*64, r0 = blockIdx.y*64;
  int tx = threadIdx.x, ty = threadIdx.y;     // 16 x 16
  #pragma unroll
  for (int i = ty; i < 64; i += 16){
    float4 v = *(const float4*)&src[(size_t)(r0+i)*Cc + c0 + tx*4];
    tile[i][tx*4+0] = v.x; tile[i][tx*4+1] = v.y;
    tile[i][tx*4+2] = v.z; tile[i][tx*4+3] = v.w;
  }
  __syncthreads();
  #pragma unroll
  for (int i = ty; i < 64; i += 16){
    ushort4 o = make_ushort4(f2bf(tile[tx*4+0][i]), f2bf(tile[tx*4+1][i]),
                             f2bf(tile[tx*4+2][i]), f2bf(tile[tx*4+3][i]));
    *(ushort4*)&dst[(size_t)(c0+i)*R + r0 + tx*4] = o;
  }
}

// LDS tiles: [128 rows][64 K-elems] bf16 (128B rows). XOR-swizzle (T2, rule 21):
// physical 16B-chunk p of row r holds logical chunk (p ^ (r&7)).
// Stage source k-offset = ((lane&7)^((lane>>3)&7))*8 elems (linear LDS dest).
// Read logical chunk c at row r (r&7 == lane&7): phys offset = (c^(lane&7))*8.

// ---------------- GEMM1: h = silu(Xg@w1 + b1) * (Xg@w3 + b3) ----------------
// Tile 128x128, BK=64, 8 waves (2M x 4N), dual B-chain. 3-deep LDS rotation
// (144 KiB): STAGE(t+2) issued right after trailing barrier (buffer freed there),
// counted vmcnt(12) retires exactly tile t -> 2 tiles stay in flight (T3/T4).
__global__ __launch_bounds__(512,1) void gemm1_kernel(
    const u16* __restrict__ xb, const u16* __restrict__ w1t, const u16* __restrict__ w3t,
    const float* __restrict__ b1, const float* __restrict__ b3,
    const int* __restrict__ token_list, const int* __restrict__ offsets, const int* __restrict__ counts,
    u16* __restrict__ h)
{
  int e  = blockIdx.z;
  int Ne = counts[e];
  int m0 = blockIdx.y * 128;
  if (m0 >= Ne) return;
  int seg = offsets[e];
  int n0  = blockIdx.x * 128;

  __shared__ u16 lA [3][128*64];   // 48 KiB
  __shared__ u16 lB1[3][128*64];   // 48 KiB
  __shared__ u16 lB3[3][128*64];   // 48 KiB

  int tid = threadIdx.x;
  int wid = tid >> 6, lane = tid & 63;
  int wr = wid >> 2, wc = wid & 3;          // 2 x 4 wave grid

  const int srcsw = (((lane&7) ^ ((lane>>3)&7))) * 8;

  size_t gA[2], gB[2];
  #pragma unroll
  for (int i=0;i<2;i++){
    int r  = wid*16 + i*8 + (lane>>3);
    int rr = m0 + r; if (rr > Ne-1) rr = Ne-1;
    int tok = token_list[seg + rr];
    gA[i] = (size_t)tok * C_DIM + srcsw;
    int n  = n0 + wid*16 + i*8 + (lane>>3);
    gB[i] = ((size_t)e*HID_DIM + n) * C_DIM + srcsw;
  }

  f32x4 acc1[4][2], acc3[4][2];
  #pragma unroll
  for (int a=0;a<4;a++)
    #pragma unroll
    for (int b=0;b<2;b++){ acc1[a][b] = (f32x4){0.f,0.f,0.f,0.f}; acc3[a][b] = (f32x4){0.f,0.f,0.f,0.f}; }

  auto STAGE = [&](int t, int b){   // 6 loads/thread
    int k0 = t*64;
    #pragma unroll
    for (int i=0;i<2;i++){
      int lds_off = (wid*16 + i*8) * 64;
      async_copy16(xb  + gA[i] + k0, &lA [b][lds_off]);
      async_copy16(w1t + gB[i] + k0, &lB1[b][lds_off]);
      async_copy16(w3t + gB[i] + k0, &lB3[b][lds_off]);
    }
  };

  auto COMPUTE = [&](int b){
    #pragma unroll
    for (int ks=0; ks<2; ks++){
      int kkS = ((ks*4 + (lane>>4)) ^ (lane&7)) * 8;
      bf16x8 af[4], b1f[2], b3f[2];
      #pragma unroll
      for (int mi=0;mi<4;mi++) af[mi]  = *(const bf16x8*)&lA [b][(wr*64+mi*16+(lane&15))*64 + kkS];
      #pragma unroll
      for (int nj=0;nj<2;nj++){ b1f[nj] = *(const bf16x8*)&lB1[b][(wc*32+nj*16+(lane&15))*64 + kkS];
                                b3f[nj] = *(const bf16x8*)&lB3[b][(wc*32+nj*16+(lane&15))*64 + kkS]; }
      __builtin_amdgcn_s_setprio(1);
      #pragma unroll
      for (int mi=0;mi<4;mi++)
        #pragma unroll
        for (int nj=0;nj<2;nj++){
          acc1[mi][nj] = __builtin_amdgcn_mfma_f32_16x16x32_bf16(af[mi], b1f[nj], acc1[mi][nj], 0,0,0);
          acc3[mi][nj] = __builtin_amdgcn_mfma_f32_16x16x32_bf16(af[mi], b3f[nj], acc3[mi][nj], 0,0,0);
        }
      __builtin_amdgcn_s_setprio(0);
    }
  };

  const int NT = C_DIM/64;   // 16
  STAGE(0,0); STAGE(1,1);
  int cb = 0, sb = 2;
  #pragma unroll 1
  for (int t=0; t<NT-2; ++t){
    STAGE(t+2, sb);               // overwrites buffer freed at previous trailing barrier
    WAIT_VM(12);                  // retire tile t (2 tiles remain in flight)
    BAR_ENTER();
    COMPUTE(cb);
    BAR_EXIT();
    cb = (cb+1==3)?0:cb+1; sb = (sb+1==3)?0:sb+1;
  }
  WAIT_VM(6);  BAR_ENTER(); COMPUTE(cb); BAR_EXIT();
  cb = (cb+1==3)?0:cb+1;
  WAIT_VM(0);  BAR_ENTER(); COMPUTE(cb);

  const float* b1p = b1 + (size_t)e*HID_DIM + n0;
  const float* b3p = b3 + (size_t)e*HID_DIM + n0;
  #pragma unroll
  for (int nj=0;nj<2;nj++){
    int nl = wc*32 + nj*16 + (lane&15);
    float bb1 = b1p[nl], bb3 = b3p[nl];
    #pragma unroll
    for (int mi=0;mi<4;mi++){
      #pragma unroll
      for (int r=0;r<4;r++){
        int ml = wr*64 + mi*16 + (lane>>4)*4 + r;
        int m  = m0 + ml;
        if (m < Ne){
          float a = acc1[mi][nj][r] + bb1;
          float b = acc3[mi][nj][r] + bb3;
          float hv = (a / (1.f + __expf(-a))) * b;   // silu(a)*b
          h[(size_t)(seg+m)*HID_DIM + n0 + nl] = f2bf(hv);
        }
      }
    }
  }
}

// ---------------- GEMM2: ybuf[pos] = w * (h @ w2 + b2), bf16 contiguous write ----------------
// Tile 128x128, BK=64, 8 waves (2M x 4N). 4-deep LDS rotation (128 KiB):
// STAGE(t+3), vmcnt(12) retires tile t -> 3 tiles in flight.
__global__ __launch_bounds__(512,1) void gemm2_kernel(
    const u16* __restrict__ h, const u16* __restrict__ w2t, const float* __restrict__ b2,
    const float* __restrict__ token_w,
    const int* __restrict__ offsets, const int* __restrict__ counts,
    u16* __restrict__ ybuf)
{
  int e  = blockIdx.z;
  int Ne = counts[e];
  int m0 = blockIdx.y * 128;
  if (m0 >= Ne) return;
  int seg = offsets[e];
  int n0  = blockIdx.x * 128;

  __shared__ u16 lA[4][128*64];   // 64 KiB
  __shared__ u16 lB[4][128*64];   // 64 KiB
  int tid=threadIdx.x, wid=tid>>6, lane=tid&63, wr=wid>>2, wc=wid&3;

  const int srcsw = (((lane&7) ^ ((lane>>3)&7))) * 8;

  size_t gA[2], gB[2];
  #pragma unroll
  for (int i=0;i<2;i++){
    int r  = wid*16 + i*8 + (lane>>3);
    int rr = m0 + r; if (rr > Ne-1) rr = Ne-1;
    gA[i] = (size_t)(seg + rr)*HID_DIM + srcsw;
    int n  = n0 + wid*16 + i*8 + (lane>>3);
    gB[i] = ((size_t)e*C_DIM + n) * HID_DIM + srcsw;
  }

  f32x4 acc[4][2];
  #pragma unroll
  for (int a=0;a<4;a++)
    #pragma unroll
    for (int b=0;b<2;b++) acc[a][b] = (f32x4){0.f,0.f,0.f,0.f};

  auto STAGE = [&](int t, int b){   // 4 loads/thread
    int k0 = t*64;
    #pragma unroll
    for (int i=0;i<2;i++){
      int lds_off = (wid*16 + i*8) * 64;
      async_copy16(h   + gA[i] + k0, &lA[b][lds_off]);
      async_copy16(w2t + gB[i] + k0, &lB[b][lds_off]);
    }
  };

  auto COMPUTE = [&](int b){
    #pragma unroll
    for (int ks=0; ks<2; ks++){
      int kkS = ((ks*4 + (lane>>4)) ^ (lane&7)) * 8;
      bf16x8 af[4], bf[2];
      #pragma unroll
      for (int mi=0;mi<4;mi++) af[mi] = *(const bf16x8*)&lA[b][(wr*64+mi*16+(lane&15))*64 + kkS];
      #pragma unroll
      for (int nj=0;nj<2;nj++) bf[nj] = *(const bf16x8*)&lB[b][(wc*32+nj*16+(lane&15))*64 + kkS];
      __builtin_amdgcn_s_setprio(1);
      #pragma unroll
      for (int mi=0;mi<4;mi++)
        #pragma unroll
        for (int nj=0;nj<2;nj++)
          acc[mi][nj] = __builtin_amdgcn_mfma_f32_16x16x32_bf16(af[mi], bf[nj], acc[mi][nj], 0,0,0);
      __builtin_amdgcn_s_setprio(0);
    }
  };

  const int NT = HID_DIM/64;   // 64
  STAGE(0,0); STAGE(1,1); STAGE(2,2);
  #pragma unroll 1
  for (int t=0; t<NT-3; ++t){
    STAGE(t+3, (t+3)&3);
    WAIT_VM(12);
    BAR_ENTER();
    COMPUTE(t&3);
    BAR_EXIT();
  }
  WAIT_VM(8);  BAR_ENTER(); COMPUTE((NT-3)&3); BAR_EXIT();
  WAIT_VM(4);  BAR_ENTER(); COMPUTE((NT-2)&3); BAR_EXIT();
  WAIT_VM(0);  BAR_ENTER(); COMPUTE((NT-1)&3);

  const float* b2p = b2 + (size_t)e*C_DIM + n0;
  #pragma unroll
  for (int mi=0;mi<4;mi++){
    #pragma unroll
    for (int r=0;r<4;r++){
      int ml = wr*64 + mi*16 + (lane>>4)*4 + r;
      int m  = m0 + ml;
      if (m < Ne){
        float w = token_w[seg+m];
        #pragma unroll
        for (int nj=0;nj<2;nj++){
          int nl = wc*32 + nj*16 + (lane&15);
          ybuf[(size_t)(seg+m)*C_DIM + n0 + nl] = f2bf((acc[mi][nj][r] + b2p[nl]) * w);
        }
      }
    }
  }
}

// ---------------- combine: y[t] = ybuf[p0] + ybuf[p1] (bf16 in, fp32 out) ----------------
__global__ __launch_bounds__(256) void combine_kernel(
    const u16* __restrict__ ybuf, const int* __restrict__ pos_of_slot, float* __restrict__ y)
{
  int t = blockIdx.x;
  int p0 = pos_of_slot[t*2+0], p1 = pos_of_slot[t*2+1];
  int c = threadIdx.x;
  ushort4 a = ((const ushort4*)(ybuf + (size_t)p0*C_DIM))[c];
  ushort4 b = ((const ushort4*)(ybuf + (size_t)p1*C_DIM))[c];
  float4 o = make_float4(bf2f(a.x)+bf2f(b.x), bf2f(a.y)+bf2f(b.y),
                         bf2f(a.z)+bf2f(b.z), bf2f(a.w)+bf2f(b.w));
  ((float4*)(y + (size_t)t*C_DIM))[c] = o;
}

// ---------------- host ----------------
extern "C" void kernel_launch(void* const* d_in, const int* in_sizes, int n_in,
                              void* d_out, int out_size, void* d_ws, size_t ws_size,
                              hipStream_t stream)
{
  const float* x    = (const float*)d_in[0];
  const float* wg_w = (const float*)d_in[1];
  const float* wg_b = (const float*)d_in[2];
  const float* w1   = (const float*)d_in[3];
  const float* b1   = (const float*)d_in[4];
  const float* w3   = (const float*)d_in[5];
  const float* b3   = (const float*)d_in[6];
  const float* w2   = (const float*)d_in[7];
  const float* b2   = (const float*)d_in[8];

  float* y   = (float*)d_out;                  // S*C
  float* aux = y + (size_t)S_TOK*C_DIM;        // 1 scalar

  char* ws = (char*)d_ws;
  size_t off = 0;
  auto alloc = [&](size_t bytes) -> void* {
    void* p = ws + off;
    off += (bytes + 255) & ~(size_t)255;
    return p;
  };
  u16*  xb        = (u16*)  alloc((size_t)S_TOK*C_DIM*2);
  u16*  w1t       = (u16*)  alloc((size_t)E_NUM*HID_DIM*C_DIM*2);   // dead after gemm1
  u16*  w3t       = (u16*)  alloc((size_t)E_NUM*HID_DIM*C_DIM*2);
  u16*  w2t       = (u16*)  alloc((size_t)E_NUM*C_DIM*HID_DIM*2);
  u16*  h         = (u16*)  alloc((size_t)S_TOK*2*HID_DIM*2);
  int*  token_list= (int*)  alloc((size_t)S_TOK*2*4);
  float* token_w  = (float*)alloc((size_t)S_TOK*2*4);
  int*  top_idx   = (int*)  alloc((size_t)S_TOK*2*4);
  float* top_val  = (float*)alloc((size_t)S_TOK*2*4);
  int*  pos_of_slot=(int*)  alloc((size_t)S_TOK*2*4);
  char* stats     = (char*) alloc(4096);
  float* imp_sum  = (float*)(stats);
  int*   cnt1     = (int*)  (stats + 64);
  int*   counts   = (int*)  (stats + 128);
  int*   offsets  = (int*)  (stats + 192);
  int*   cursor   = (int*)  (stats + 256);
  // ybuf (S*2 x C bf16 = 32 MiB) aliases w1t (64 MiB): dead after gemm1, stream-ordered.
  u16* ybuf = (u16*)w1t;
  (void)in_sizes; (void)n_in; (void)out_size; (void)ws_size;

  hipMemsetAsync(stats, 0, 512, stream);

  dim3 tb(16,16);
  transpose_kernel<<<dim3(HID_DIM/64, C_DIM/64, E_NUM), tb, 0, stream>>>(w1, w1t, C_DIM, HID_DIM);
  transpose_kernel<<<dim3(HID_DIM/64, C_DIM/64, E_NUM), tb, 0, stream>>>(w3, w3t, C_DIM, HID_DIM);
  transpose_kernel<<<dim3(C_DIM/64, HID_DIM/64, E_NUM), tb, 0, stream>>>(w2, w2t, HID_DIM, C_DIM);

  gate_kernel<<<S_TOK/4, 256, 0, stream>>>(x, wg_w, wg_b, xb, top_idx, top_val, imp_sum, cnt1, counts);
  scan_kernel<<<1, 64, 0, stream>>>(counts, offsets, cursor, imp_sum, cnt1, aux);
  scatter_kernel<<<S_TOK/256, 256, 0, stream>>>(top_idx, top_val, cursor, token_list, token_w, pos_of_slot);

  gemm1_kernel<<<dim3(HID_DIM/128, S_TOK/128, E_NUM), 512, 0, stream>>>(
      xb, w1t, w3t, b1, b3, token_list, offsets, counts, h);
  gemm2_kernel<<<dim3(C_DIM/128, S_TOK/128, E_NUM), 512, 0, stream>>>(
      h, w2t, b2, token_w, offsets, counts, ybuf);
  combine_kernel<<<S_TOK, 256, 0, stream>>>(ybuf, pos_of_slot, y);
}

// Round 8
// 802.571 us; speedup vs baseline: 1.3900x; 1.3900x over previous
//
#include <hip/hip_runtime.h>

#define S_TOK 8192
#define C_DIM 1024
#define E_NUM 8
#define HID_DIM 4096

typedef unsigned short u16;
typedef __bf16 bf16x8 __attribute__((ext_vector_type(8)));
typedef float f32x4 __attribute__((ext_vector_type(4)));

__device__ __forceinline__ u16 f2bf(float f){
  union { float f; unsigned u; } v; v.f = f;
  unsigned r = v.u + 0x7fffu + ((v.u >> 16) & 1u);
  return (u16)(r >> 16);
}
__device__ __forceinline__ float bf2f(u16 b){
  union { unsigned u; float f; } v; v.u = ((unsigned)b) << 16; return v.f;
}

__device__ __forceinline__ void async_copy16(const void* g, void* l){
  __builtin_amdgcn_global_load_lds((const __attribute__((address_space(1))) void*)g,
                                   (__attribute__((address_space(3))) void*)l, 16, 0, 0);
}

// ---------------- gate: logits -> softmax -> top2 -> stats; also emits xb (bf16 x) ----------------
__global__ __launch_bounds__(256) void gate_kernel(
    const float* __restrict__ x, const float* __restrict__ wg_w, const float* __restrict__ wg_b,
    u16* __restrict__ xb,
    int* __restrict__ top_idx, float* __restrict__ top_val,
    float* __restrict__ imp_sum, int* __restrict__ cnt_top1, int* __restrict__ counts)
{
  __shared__ float s_imp[E_NUM];
  __shared__ int   s_c1[E_NUM], s_cnt[E_NUM];
  if (threadIdx.x < E_NUM){ s_imp[threadIdx.x]=0.f; s_c1[threadIdx.x]=0; s_cnt[threadIdx.x]=0; }
  __syncthreads();

  int wid = threadIdx.x >> 6, lane = threadIdx.x & 63;
  int t = blockIdx.x * 4 + wid;
  const float4* xr4 = (const float4*)(x + (size_t)t * C_DIM);
  u16* xbr = xb + (size_t)t * C_DIM;
  float acc[E_NUM];
  #pragma unroll
  for (int e=0;e<E_NUM;e++) acc[e]=0.f;
  #pragma unroll
  for (int c4 = 0; c4 < C_DIM/4/64; c4++){
    int c = (c4*64 + lane);
    float4 xv = xr4[c];
    ushort4 o = make_ushort4(f2bf(xv.x), f2bf(xv.y), f2bf(xv.z), f2bf(xv.w));
    *(ushort4*)&xbr[c*4] = o;
    const float* wr = wg_w + (size_t)c * 4 * E_NUM;
    #pragma unroll
    for (int e=0;e<E_NUM;e++)
      acc[e] += xv.x*wr[e] + xv.y*wr[E_NUM+e] + xv.z*wr[2*E_NUM+e] + xv.w*wr[3*E_NUM+e];
  }
  #pragma unroll
  for (int e=0;e<E_NUM;e++){
    float v = acc[e];
    #pragma unroll
    for (int off=32; off>0; off>>=1) v += __shfl_xor(v, off, 64);
    acc[e] = v + wg_b[e];
  }
  float mx = acc[0];
  #pragma unroll
  for (int e=1;e<E_NUM;e++) mx = fmaxf(mx, acc[e]);
  float sum = 0.f;
  #pragma unroll
  for (int e=0;e<E_NUM;e++){ acc[e] = __expf(acc[e]-mx); sum += acc[e]; }
  float inv = 1.f/sum;
  #pragma unroll
  for (int e=0;e<E_NUM;e++) acc[e] *= inv;
  int i1=0; float v1=acc[0];
  #pragma unroll
  for (int e=1;e<E_NUM;e++) if (acc[e] > v1){ v1=acc[e]; i1=e; }
  int i2=-1; float v2=-1.f;
  #pragma unroll
  for (int e=0;e<E_NUM;e++) if (e!=i1 && acc[e] > v2){ v2=acc[e]; i2=e; }

  if (lane==0){
    top_idx[t*2+0]=i1; top_idx[t*2+1]=i2;
    top_val[t*2+0]=v1; top_val[t*2+1]=v2;
    #pragma unroll
    for (int e=0;e<E_NUM;e++) atomicAdd(&s_imp[e], acc[e]);
    atomicAdd(&s_c1[i1],1);
    atomicAdd(&s_cnt[i1],1); atomicAdd(&s_cnt[i2],1);
  }
  __syncthreads();
  if (threadIdx.x < E_NUM){
    atomicAdd(&imp_sum[threadIdx.x], s_imp[threadIdx.x]);
    atomicAdd(&cnt_top1[threadIdx.x], s_c1[threadIdx.x]);
    atomicAdd(&counts[threadIdx.x], s_cnt[threadIdx.x]);
  }
}

// ---------------- scan: offsets, cursors, aux ----------------
__global__ void scan_kernel(const int* __restrict__ counts, int* __restrict__ offsets,
                            int* __restrict__ cursor, const float* __restrict__ imp_sum,
                            const int* __restrict__ cnt_top1, float* __restrict__ aux_out)
{
  if (threadIdx.x==0 && blockIdx.x==0){
    int off=0;
    #pragma unroll
    for (int e=0;e<E_NUM;e++){ offsets[e]=off; cursor[e]=off; off+=counts[e]; }
    float aux=0.f;
    #pragma unroll
    for (int e=0;e<E_NUM;e++)
      aux += (imp_sum[e]/(float)S_TOK) * ((float)cnt_top1[e]/(float)S_TOK);
    aux_out[0] = aux * (float)E_NUM;
  }
}

// ---------------- scatter ----------------
__global__ __launch_bounds__(256) void scatter_kernel(
    const int* __restrict__ top_idx, const float* __restrict__ top_val,
    int* __restrict__ cursor, int* __restrict__ token_list, float* __restrict__ token_w,
    int* __restrict__ pos_of_slot)
{
  int t = blockIdx.x*256 + threadIdx.x;
  #pragma unroll
  for (int k=0;k<2;k++){
    int e = top_idx[t*2+k];
    int pos = atomicAdd(&cursor[e], 1);
    token_list[pos] = t;
    token_w[pos]    = top_val[t*2+k];
    pos_of_slot[t*2+k] = pos;
  }
}

// ---------------- weight transpose fp32 (R x Cc) -> bf16 (Cc x R) ----------------
// 64(rows) x 128(cols) tile per block; block (16,16); float4 loads, ushort4 stores.
__global__ __launch_bounds__(256) void transpose_kernel(const float* __restrict__ in, u16* __restrict__ out,
                                                        int R, int Cc)
{
  __shared__ float tile[64][129];
  int e = blockIdx.z;
  const float* src = in  + (size_t)e*R*Cc;
  u16*         dst = out + (size_t)e*R*Cc;
  int c0 = blockIdx.x*128, r0 = blockIdx.y*64;
  int tx = threadIdx.x, ty = threadIdx.y;     // 16 x 16
  #pragma unroll
  for (int i = ty; i < 64; i += 16){
    const float* s = &src[(size_t)(r0+i)*Cc + c0 + tx*8];
    float4 v0 = *(const float4*)&s[0];
    float4 v1 = *(const float4*)&s[4];
    tile[i][tx*8+0] = v0.x; tile[i][tx*8+1] = v0.y;
    tile[i][tx*8+2] = v0.z; tile[i][tx*8+3] = v0.w;
    tile[i][tx*8+4] = v1.x; tile[i][tx*8+5] = v1.y;
    tile[i][tx*8+6] = v1.z; tile[i][tx*8+7] = v1.w;
  }
  __syncthreads();
  #pragma unroll
  for (int i = ty; i < 128; i += 16){
    ushort4 o = make_ushort4(f2bf(tile[tx*4+0][i]), f2bf(tile[tx*4+1][i]),
                             f2bf(tile[tx*4+2][i]), f2bf(tile[tx*4+3][i]));
    *(ushort4*)&dst[(size_t)(c0+i)*R + r0 + tx*4] = o;
  }
}

// LDS tiles: [rows][64 K-elems] bf16 (128B rows). XOR-swizzle (T2, rule 21):
// physical 16B-chunk p of row r holds logical chunk (p ^ (r&7)).
// Stage source k-offset = ((lane&7)^((lane>>3)&7))*8 elems (linear LDS dest).
// Read logical chunk c at row r (r&7 == lane&7): phys offset = (c^(lane&7))*8.

// ---------------- GEMM1: h = silu(Xg@w1 + b1) * (Xg@w3 + b3) ----------------
// r6 structure (validated 360us): 8 waves (2M x 4N), tile 128x128, BK=64, dual B-chain,
// single-buffered LDS (48 KiB -> 3 blocks/CU; cross-block overlap covers the drain).
__global__ __launch_bounds__(512,1) void gemm1_kernel(
    const u16* __restrict__ xb, const u16* __restrict__ w1t, const u16* __restrict__ w3t,
    const float* __restrict__ b1, const float* __restrict__ b3,
    const int* __restrict__ token_list, const int* __restrict__ offsets, const int* __restrict__ counts,
    u16* __restrict__ h)
{
  int e  = blockIdx.z;
  int Ne = counts[e];
  int m0 = blockIdx.y * 128;
  if (m0 >= Ne) return;
  int seg = offsets[e];
  int n0  = blockIdx.x * 128;

  __shared__ u16 lA [128*64];
  __shared__ u16 lB1[128*64];
  __shared__ u16 lB3[128*64];

  int tid = threadIdx.x;
  int wid = tid >> 6, lane = tid & 63;
  int wr = wid >> 2, wc = wid & 3;          // 2 x 4 wave grid

  const int srcsw = (((lane&7) ^ ((lane>>3)&7))) * 8;   // swizzled k-offset (elems)

  size_t gA[2], gB[2];
  #pragma unroll
  for (int i=0;i<2;i++){
    int r  = wid*16 + i*8 + (lane>>3);
    int rr = m0 + r; if (rr > Ne-1) rr = Ne-1;
    int tok = token_list[seg + rr];
    gA[i] = (size_t)tok * C_DIM + srcsw;
    int n  = n0 + wid*16 + i*8 + (lane>>3);
    gB[i] = ((size_t)e*HID_DIM + n) * C_DIM + srcsw;
  }

  f32x4 acc1[4][2], acc3[4][2];
  #pragma unroll
  for (int a=0;a<4;a++)
    #pragma unroll
    for (int b=0;b<2;b++){ acc1[a][b] = (f32x4){0.f,0.f,0.f,0.f}; acc3[a][b] = (f32x4){0.f,0.f,0.f,0.f}; }

  for (int k0=0; k0<C_DIM; k0+=64){
    #pragma unroll
    for (int i=0;i<2;i++){
      int lds_off = (wid*16 + i*8) * 64;
      async_copy16(xb  + gA[i] + k0, &lA [lds_off]);
      async_copy16(w1t + gB[i] + k0, &lB1[lds_off]);
      async_copy16(w3t + gB[i] + k0, &lB3[lds_off]);
    }
    __syncthreads();
    #pragma unroll
    for (int ks=0; ks<2; ks++){
      int kkS = ((ks*4 + (lane>>4)) ^ (lane&7)) * 8;   // swizzled read offset
      bf16x8 af[4], b1f[2], b3f[2];
      #pragma unroll
      for (int mi=0;mi<4;mi++) af[mi]  = *(const bf16x8*)&lA [(wr*64+mi*16+(lane&15))*64 + kkS];
      #pragma unroll
      for (int nj=0;nj<2;nj++){ b1f[nj] = *(const bf16x8*)&lB1[(wc*32+nj*16+(lane&15))*64 + kkS];
                                b3f[nj] = *(const bf16x8*)&lB3[(wc*32+nj*16+(lane&15))*64 + kkS]; }
      #pragma unroll
      for (int mi=0;mi<4;mi++)
        #pragma unroll
        for (int nj=0;nj<2;nj++){
          acc1[mi][nj] = __builtin_amdgcn_mfma_f32_16x16x32_bf16(af[mi], b1f[nj], acc1[mi][nj], 0,0,0);
          acc3[mi][nj] = __builtin_amdgcn_mfma_f32_16x16x32_bf16(af[mi], b3f[nj], acc3[mi][nj], 0,0,0);
        }
    }
    __syncthreads();
  }

  const float* b1p = b1 + (size_t)e*HID_DIM + n0;
  const float* b3p = b3 + (size_t)e*HID_DIM + n0;
  #pragma unroll
  for (int nj=0;nj<2;nj++){
    int nl = wc*32 + nj*16 + (lane&15);
    float bb1 = b1p[nl], bb3 = b3p[nl];
    #pragma unroll
    for (int mi=0;mi<4;mi++){
      #pragma unroll
      for (int r=0;r<4;r++){
        int ml = wr*64 + mi*16 + (lane>>4)*4 + r;
        int m  = m0 + ml;
        if (m < Ne){
          float a = acc1[mi][nj][r] + bb1;
          float b = acc3[mi][nj][r] + bb3;
          float hv = (a / (1.f + __expf(-a))) * b;   // silu(a)*b
          h[(size_t)(seg+m)*HID_DIM + n0 + nl] = f2bf(hv);
        }
      }
    }
  }
}

// ---------------- GEMM2: ybuf[pos] = w * (h @ w2 + b2), bf16 contiguous write ----------------
// Retiled to 128x256 (8 waves 2M x 4N, per-wave 64x64): ds_read:MFMA ratio 0.5
// (was 0.75 at 128x128), LDS 48 KiB -> 3 blocks/CU, acc in AGPRs.
__global__ __launch_bounds__(512,1) void gemm2_kernel(
    const u16* __restrict__ h, const u16* __restrict__ w2t, const float* __restrict__ b2,
    const float* __restrict__ token_w,
    const int* __restrict__ offsets, const int* __restrict__ counts,
    u16* __restrict__ ybuf)
{
  int e  = blockIdx.z;
  int Ne = counts[e];
  int m0 = blockIdx.y * 128;
  if (m0 >= Ne) return;
  int seg = offsets[e];
  int n0  = blockIdx.x * 256;

  __shared__ u16 lA[128*64];   // 16 KiB
  __shared__ u16 lB[256*64];   // 32 KiB
  int tid=threadIdx.x, wid=tid>>6, lane=tid&63, wr=wid>>2, wc=wid&3;

  const int srcsw = (((lane&7) ^ ((lane>>3)&7))) * 8;

  size_t gA[2], gB[4];
  #pragma unroll
  for (int i=0;i<2;i++){
    int r  = wid*16 + i*8 + (lane>>3);
    int rr = m0 + r; if (rr > Ne-1) rr = Ne-1;
    gA[i] = (size_t)(seg + rr)*HID_DIM + srcsw;
  }
  #pragma unroll
  for (int i=0;i<4;i++){
    int n  = n0 + i*64 + wid*8 + (lane>>3);
    gB[i] = ((size_t)e*C_DIM + n) * HID_DIM + srcsw;
  }

  f32x4 acc[4][4];
  #pragma unroll
  for (int a=0;a<4;a++)
    #pragma unroll
    for (int b=0;b<4;b++) acc[a][b] = (f32x4){0.f,0.f,0.f,0.f};

  for (int k0=0; k0<HID_DIM; k0+=64){
    #pragma unroll
    for (int i=0;i<2;i++)
      async_copy16(h   + gA[i] + k0, &lA[(wid*16 + i*8)*64]);
    #pragma unroll
    for (int i=0;i<4;i++)
      async_copy16(w2t + gB[i] + k0, &lB[(i*64 + wid*8)*64]);
    __syncthreads();
    #pragma unroll
    for (int ks=0; ks<2; ks++){
      int kkS = ((ks*4 + (lane>>4)) ^ (lane&7)) * 8;
      bf16x8 af[4], bf[4];
      #pragma unroll
      for (int mi=0;mi<4;mi++) af[mi] = *(const bf16x8*)&lA[(wr*64+mi*16+(lane&15))*64 + kkS];
      #pragma unroll
      for (int nj=0;nj<4;nj++) bf[nj] = *(const bf16x8*)&lB[(wc*64+nj*16+(lane&15))*64 + kkS];
      #pragma unroll
      for (int mi=0;mi<4;mi++)
        #pragma unroll
        for (int nj=0;nj<4;nj++)
          acc[mi][nj] = __builtin_amdgcn_mfma_f32_16x16x32_bf16(af[mi], bf[nj], acc[mi][nj], 0,0,0);
    }
    __syncthreads();
  }

  const float* b2p = b2 + (size_t)e*C_DIM + n0;
  #pragma unroll
  for (int mi=0;mi<4;mi++){
    #pragma unroll
    for (int r=0;r<4;r++){
      int ml = wr*64 + mi*16 + (lane>>4)*4 + r;
      int m  = m0 + ml;
      if (m < Ne){
        float w = token_w[seg+m];
        #pragma unroll
        for (int nj=0;nj<4;nj++){
          int nl = wc*64 + nj*16 + (lane&15);
          ybuf[(size_t)(seg+m)*C_DIM + n0 + nl] = f2bf((acc[mi][nj][r] + b2p[nl]) * w);
        }
      }
    }
  }
}

// ---------------- combine: y[t] = ybuf[p0] + ybuf[p1] (bf16 in, fp32 out) ----------------
__global__ __launch_bounds__(256) void combine_kernel(
    const u16* __restrict__ ybuf, const int* __restrict__ pos_of_slot, float* __restrict__ y)
{
  int t = blockIdx.x;
  int p0 = pos_of_slot[t*2+0], p1 = pos_of_slot[t*2+1];
  int c = threadIdx.x;
  ushort4 a = ((const ushort4*)(ybuf + (size_t)p0*C_DIM))[c];
  ushort4 b = ((const ushort4*)(ybuf + (size_t)p1*C_DIM))[c];
  float4 o = make_float4(bf2f(a.x)+bf2f(b.x), bf2f(a.y)+bf2f(b.y),
                         bf2f(a.z)+bf2f(b.z), bf2f(a.w)+bf2f(b.w));
  ((float4*)(y + (size_t)t*C_DIM))[c] = o;
}

// ---------------- host ----------------
extern "C" void kernel_launch(void* const* d_in, const int* in_sizes, int n_in,
                              void* d_out, int out_size, void* d_ws, size_t ws_size,
                              hipStream_t stream)
{
  const float* x    = (const float*)d_in[0];
  const float* wg_w = (const float*)d_in[1];
  const float* wg_b = (const float*)d_in[2];
  const float* w1   = (const float*)d_in[3];
  const float* b1   = (const float*)d_in[4];
  const float* w3   = (const float*)d_in[5];
  const float* b3   = (const float*)d_in[6];
  const float* w2   = (const float*)d_in[7];
  const float* b2   = (const float*)d_in[8];

  float* y   = (float*)d_out;                  // S*C
  float* aux = y + (size_t)S_TOK*C_DIM;        // 1 scalar

  char* ws = (char*)d_ws;
  size_t off = 0;
  auto alloc = [&](size_t bytes) -> void* {
    void* p = ws + off;
    off += (bytes + 255) & ~(size_t)255;
    return p;
  };
  u16*  xb        = (u16*)  alloc((size_t)S_TOK*C_DIM*2);
  u16*  w1t       = (u16*)  alloc((size_t)E_NUM*HID_DIM*C_DIM*2);   // dead after gemm1
  u16*  w3t       = (u16*)  alloc((size_t)E_NUM*HID_DIM*C_DIM*2);
  u16*  w2t       = (u16*)  alloc((size_t)E_NUM*C_DIM*HID_DIM*2);
  u16*  h         = (u16*)  alloc((size_t)S_TOK*2*HID_DIM*2);
  int*  token_list= (int*)  alloc((size_t)S_TOK*2*4);
  float* token_w  = (float*)alloc((size_t)S_TOK*2*4);
  int*  top_idx   = (int*)  alloc((size_t)S_TOK*2*4);
  float* top_val  = (float*)alloc((size_t)S_TOK*2*4);
  int*  pos_of_slot=(int*)  alloc((size_t)S_TOK*2*4);
  char* stats     = (char*) alloc(4096);
  float* imp_sum  = (float*)(stats);
  int*   cnt1     = (int*)  (stats + 64);
  int*   counts   = (int*)  (stats + 128);
  int*   offsets  = (int*)  (stats + 192);
  int*   cursor   = (int*)  (stats + 256);
  // ybuf (S*2 x C bf16 = 32 MiB) aliases w1t (64 MiB): dead after gemm1, stream-ordered.
  u16* ybuf = (u16*)w1t;
  (void)in_sizes; (void)n_in; (void)out_size; (void)ws_size;

  hipMemsetAsync(stats, 0, 512, stream);

  dim3 tb(16,16);
  transpose_kernel<<<dim3(HID_DIM/128, C_DIM/64, E_NUM), tb, 0, stream>>>(w1, w1t, C_DIM, HID_DIM);
  transpose_kernel<<<dim3(HID_DIM/128, C_DIM/64, E_NUM), tb, 0, stream>>>(w3, w3t, C_DIM, HID_DIM);
  transpose_kernel<<<dim3(C_DIM/128, HID_DIM/64, E_NUM), tb, 0, stream>>>(w2, w2t, HID_DIM, C_DIM);

  gate_kernel<<<S_TOK/4, 256, 0, stream>>>(x, wg_w, wg_b, xb, top_idx, top_val, imp_sum, cnt1, counts);
  scan_kernel<<<1, 64, 0, stream>>>(counts, offsets, cursor, imp_sum, cnt1, aux);
  scatter_kernel<<<S_TOK/256, 256, 0, stream>>>(top_idx, top_val, cursor, token_list, token_w, pos_of_slot);

  gemm1_kernel<<<dim3(HID_DIM/128, S_TOK/128, E_NUM), 512, 0, stream>>>(
      xb, w1t, w3t, b1, b3, token_list, offsets, counts, h);
  gemm2_kernel<<<dim3(C_DIM/256, S_TOK/128, E_NUM), 512, 0, stream>>>(
      h, w2t, b2, token_w, offsets, counts, ybuf);
  combine_kernel<<<S_TOK, 256, 0, stream>>>(ybuf, pos_of_slot, y);
}

// Round 9
// 795.915 us; speedup vs baseline: 1.4016x; 1.0084x over previous
//
#include <hip/hip_runtime.h>

#define S_TOK 8192
#define C_DIM 1024
#define E_NUM 8
#define HID_DIM 4096

typedef unsigned short u16;
typedef __bf16 bf16x8 __attribute__((ext_vector_type(8)));
typedef float f32x4 __attribute__((ext_vector_type(4)));
typedef unsigned short ushort8v __attribute__((ext_vector_type(8)));

__device__ __forceinline__ u16 f2bf(float f){
  union { float f; unsigned u; } v; v.f = f;
  unsigned r = v.u + 0x7fffu + ((v.u >> 16) & 1u);
  return (u16)(r >> 16);
}
__device__ __forceinline__ float bf2f(u16 b){
  union { unsigned u; float f; } v; v.u = ((unsigned)b) << 16; return v.f;
}

__device__ __forceinline__ void async_copy16(const void* g, void* l){
  __builtin_amdgcn_global_load_lds((const __attribute__((address_space(1))) void*)g,
                                   (__attribute__((address_space(3))) void*)l, 16, 0, 0);
}

// ---------------- gate: logits -> softmax -> top2 -> stats; also emits xb (bf16 x) ----------------
__global__ __launch_bounds__(256) void gate_kernel(
    const float* __restrict__ x, const float* __restrict__ wg_w, const float* __restrict__ wg_b,
    u16* __restrict__ xb,
    int* __restrict__ top_idx, float* __restrict__ top_val,
    float* __restrict__ imp_sum, int* __restrict__ cnt_top1, int* __restrict__ counts)
{
  __shared__ float s_imp[E_NUM];
  __shared__ int   s_c1[E_NUM], s_cnt[E_NUM];
  if (threadIdx.x < E_NUM){ s_imp[threadIdx.x]=0.f; s_c1[threadIdx.x]=0; s_cnt[threadIdx.x]=0; }
  __syncthreads();

  int wid = threadIdx.x >> 6, lane = threadIdx.x & 63;
  int t = blockIdx.x * 4 + wid;
  const float4* xr4 = (const float4*)(x + (size_t)t * C_DIM);
  u16* xbr = xb + (size_t)t * C_DIM;
  float acc[E_NUM];
  #pragma unroll
  for (int e=0;e<E_NUM;e++) acc[e]=0.f;
  #pragma unroll
  for (int c4 = 0; c4 < C_DIM/4/64; c4++){
    int c = (c4*64 + lane);
    float4 xv = xr4[c];
    ushort4 o = make_ushort4(f2bf(xv.x), f2bf(xv.y), f2bf(xv.z), f2bf(xv.w));
    *(ushort4*)&xbr[c*4] = o;
    const float* wr = wg_w + (size_t)c * 4 * E_NUM;
    #pragma unroll
    for (int e=0;e<E_NUM;e++)
      acc[e] += xv.x*wr[e] + xv.y*wr[E_NUM+e] + xv.z*wr[2*E_NUM+e] + xv.w*wr[3*E_NUM+e];
  }
  #pragma unroll
  for (int e=0;e<E_NUM;e++){
    float v = acc[e];
    #pragma unroll
    for (int off=32; off>0; off>>=1) v += __shfl_xor(v, off, 64);
    acc[e] = v + wg_b[e];
  }
  float mx = acc[0];
  #pragma unroll
  for (int e=1;e<E_NUM;e++) mx = fmaxf(mx, acc[e]);
  float sum = 0.f;
  #pragma unroll
  for (int e=0;e<E_NUM;e++){ acc[e] = __expf(acc[e]-mx); sum += acc[e]; }
  float inv = 1.f/sum;
  #pragma unroll
  for (int e=0;e<E_NUM;e++) acc[e] *= inv;
  int i1=0; float v1=acc[0];
  #pragma unroll
  for (int e=1;e<E_NUM;e++) if (acc[e] > v1){ v1=acc[e]; i1=e; }
  int i2=-1; float v2=-1.f;
  #pragma unroll
  for (int e=0;e<E_NUM;e++) if (e!=i1 && acc[e] > v2){ v2=acc[e]; i2=e; }

  if (lane==0){
    top_idx[t*2+0]=i1; top_idx[t*2+1]=i2;
    top_val[t*2+0]=v1; top_val[t*2+1]=v2;
    #pragma unroll
    for (int e=0;e<E_NUM;e++) atomicAdd(&s_imp[e], acc[e]);
    atomicAdd(&s_c1[i1],1);
    atomicAdd(&s_cnt[i1],1); atomicAdd(&s_cnt[i2],1);
  }
  __syncthreads();
  if (threadIdx.x < E_NUM){
    atomicAdd(&imp_sum[threadIdx.x], s_imp[threadIdx.x]);
    atomicAdd(&cnt_top1[threadIdx.x], s_c1[threadIdx.x]);
    atomicAdd(&counts[threadIdx.x], s_cnt[threadIdx.x]);
  }
}

// ---------------- scan: offsets (real + 128-padded), cursors, aux ----------------
__global__ void scan_kernel(const int* __restrict__ counts, int* __restrict__ offsets,
                            int* __restrict__ cursor, int* __restrict__ pad_off,
                            const float* __restrict__ imp_sum,
                            const int* __restrict__ cnt_top1, float* __restrict__ aux_out)
{
  if (threadIdx.x==0 && blockIdx.x==0){
    int off=0, poff=0;
    #pragma unroll
    for (int e=0;e<E_NUM;e++){
      offsets[e]=off; cursor[e]=off; pad_off[e]=poff;
      off += counts[e];
      poff += ((counts[e]+127)>>7)<<7;
    }
    pad_off[E_NUM]=poff;
    float aux=0.f;
    #pragma unroll
    for (int e=0;e<E_NUM;e++)
      aux += (imp_sum[e]/(float)S_TOK) * ((float)cnt_top1[e]/(float)S_TOK);
    aux_out[0] = aux * (float)E_NUM;
  }
}

// ---------------- scatter ----------------
__global__ __launch_bounds__(256) void scatter_kernel(
    const int* __restrict__ top_idx, const float* __restrict__ top_val,
    int* __restrict__ cursor, int* __restrict__ token_list, float* __restrict__ token_w,
    int* __restrict__ pos_of_slot)
{
  int t = blockIdx.x*256 + threadIdx.x;
  #pragma unroll
  for (int k=0;k<2;k++){
    int e = top_idx[t*2+k];
    int pos = atomicAdd(&cursor[e], 1);
    token_list[pos] = t;
    token_w[pos]    = top_val[t*2+k];
    pos_of_slot[t*2+k] = pos;
  }
}

// ---------------- weight transpose fp32 (R x Cc) -> bf16 (Cc x R) ----------------
// 64(rows) x 128(cols) tile; block 256 threads; float4 loads, ushort8 (16B) stores.
// Handles two weight tensors in one launch via blockIdx.z (z<8: t0, else t1).
__global__ __launch_bounds__(256) void transpose2_kernel(
    const float* __restrict__ in0, const float* __restrict__ in1,
    u16* __restrict__ out0, u16* __restrict__ out1, int R, int Cc)
{
  __shared__ float tile[64][129];
  int z = blockIdx.z;
  int e = z & (E_NUM-1);
  const float* src = (z < E_NUM ? in0 : in1) + (size_t)e*R*Cc;
  u16*         dst = (z < E_NUM ? out0 : out1) + (size_t)e*R*Cc;
  int c0 = blockIdx.x*128, r0 = blockIdx.y*64;
  int tx = threadIdx.x & 15, ty = threadIdx.x >> 4;   // 16 x 16
  #pragma unroll
  for (int i = ty; i < 64; i += 16){
    const float* s = &src[(size_t)(r0+i)*Cc + c0 + tx*8];
    float4 v0 = *(const float4*)&s[0];
    float4 v1 = *(const float4*)&s[4];
    tile[i][tx*8+0] = v0.x; tile[i][tx*8+1] = v0.y;
    tile[i][tx*8+2] = v0.z; tile[i][tx*8+3] = v0.w;
    tile[i][tx*8+4] = v1.x; tile[i][tx*8+5] = v1.y;
    tile[i][tx*8+6] = v1.z; tile[i][tx*8+7] = v1.w;
  }
  __syncthreads();
  int u  = threadIdx.x;
  int cg = u & 7;          // which 8-wide r-chunk
  int rb = u >> 3;         // 0..31 base c-row
  #pragma unroll
  for (int j = 0; j < 4; j++){
    int cr = rb + 32*j;    // c-row 0..127
    ushort8v o;
    #pragma unroll
    for (int q=0;q<8;q++) o[q] = f2bf(tile[cg*8+q][cr]);
    *(ushort8v*)&dst[(size_t)(c0+cr)*R + r0 + cg*8] = o;
  }
}

// LDS tiles: [rows][64 K-elems] bf16 (128B rows). XOR-swizzle (T2, rule 21):
// physical 16B-chunk p of row r holds logical chunk (p ^ (r&7)).
// Stage source k-offset = ((lane&7)^((lane>>3)&7))*8 elems (linear LDS dest).
// Read logical chunk c at row r (r&7 == lane&7): phys offset = (c^(lane&7))*8.

// Block -> (expert, m0) via 128-aligned padded offsets: all rows of a block
// belong to one expert; padding rows are clamped on gather, skipped on store.

// ---------------- GEMM1: h = silu(Xg@w1 + b1) * (Xg@w3 + b3) ----------------
// r6 structure (validated 360us): 8 waves (2M x 4N), tile 128x128, BK=64, dual B-chain,
// single-buffered LDS (48 KiB -> 3 blocks/CU; cross-block overlap covers the drain).
__global__ __launch_bounds__(512,1) void gemm1_kernel(
    const u16* __restrict__ xb, const u16* __restrict__ w1t, const u16* __restrict__ w3t,
    const float* __restrict__ b1, const float* __restrict__ b3,
    const int* __restrict__ token_list, const int* __restrict__ offsets,
    const int* __restrict__ counts, const int* __restrict__ pad_off,
    u16* __restrict__ h)
{
  int row0 = blockIdx.y * 128;
  if (row0 >= pad_off[E_NUM]) return;
  int e = 0;
  #pragma unroll
  for (int k=1;k<E_NUM;k++) if (row0 >= pad_off[k]) e = k;
  int m0  = row0 - pad_off[e];
  int Ne  = counts[e];
  int seg = offsets[e];
  int n0  = blockIdx.x * 128;

  __shared__ u16 lA [128*64];
  __shared__ u16 lB1[128*64];
  __shared__ u16 lB3[128*64];

  int tid = threadIdx.x;
  int wid = tid >> 6, lane = tid & 63;
  int wr = wid >> 2, wc = wid & 3;          // 2 x 4 wave grid

  const int srcsw = (((lane&7) ^ ((lane>>3)&7))) * 8;   // swizzled k-offset (elems)

  size_t gA[2], gB[2];
  #pragma unroll
  for (int i=0;i<2;i++){
    int r  = wid*16 + i*8 + (lane>>3);
    int rr = m0 + r; if (rr > Ne-1) rr = Ne-1;
    int tok = token_list[seg + rr];
    gA[i] = (size_t)tok * C_DIM + srcsw;
    int n  = n0 + wid*16 + i*8 + (lane>>3);
    gB[i] = ((size_t)e*HID_DIM + n) * C_DIM + srcsw;
  }

  f32x4 acc1[4][2], acc3[4][2];
  #pragma unroll
  for (int a=0;a<4;a++)
    #pragma unroll
    for (int b=0;b<2;b++){ acc1[a][b] = (f32x4){0.f,0.f,0.f,0.f}; acc3[a][b] = (f32x4){0.f,0.f,0.f,0.f}; }

  for (int k0=0; k0<C_DIM; k0+=64){
    #pragma unroll
    for (int i=0;i<2;i++){
      int lds_off = (wid*16 + i*8) * 64;
      async_copy16(xb  + gA[i] + k0, &lA [lds_off]);
      async_copy16(w1t + gB[i] + k0, &lB1[lds_off]);
      async_copy16(w3t + gB[i] + k0, &lB3[lds_off]);
    }
    __syncthreads();
    #pragma unroll
    for (int ks=0; ks<2; ks++){
      int kkS = ((ks*4 + (lane>>4)) ^ (lane&7)) * 8;   // swizzled read offset
      bf16x8 af[4], b1f[2], b3f[2];
      #pragma unroll
      for (int mi=0;mi<4;mi++) af[mi]  = *(const bf16x8*)&lA [(wr*64+mi*16+(lane&15))*64 + kkS];
      #pragma unroll
      for (int nj=0;nj<2;nj++){ b1f[nj] = *(const bf16x8*)&lB1[(wc*32+nj*16+(lane&15))*64 + kkS];
                                b3f[nj] = *(const bf16x8*)&lB3[(wc*32+nj*16+(lane&15))*64 + kkS]; }
      #pragma unroll
      for (int mi=0;mi<4;mi++)
        #pragma unroll
        for (int nj=0;nj<2;nj++){
          acc1[mi][nj] = __builtin_amdgcn_mfma_f32_16x16x32_bf16(af[mi], b1f[nj], acc1[mi][nj], 0,0,0);
          acc3[mi][nj] = __builtin_amdgcn_mfma_f32_16x16x32_bf16(af[mi], b3f[nj], acc3[mi][nj], 0,0,0);
        }
    }
    __syncthreads();
  }

  const float* b1p = b1 + (size_t)e*HID_DIM + n0;
  const float* b3p = b3 + (size_t)e*HID_DIM + n0;
  #pragma unroll
  for (int nj=0;nj<2;nj++){
    int nl = wc*32 + nj*16 + (lane&15);
    float bb1 = b1p[nl], bb3 = b3p[nl];
    #pragma unroll
    for (int mi=0;mi<4;mi++){
      #pragma unroll
      for (int r=0;r<4;r++){
        int ml = wr*64 + mi*16 + (lane>>4)*4 + r;
        int m  = m0 + ml;
        if (m < Ne){
          float a = acc1[mi][nj][r] + bb1;
          float b = acc3[mi][nj][r] + bb3;
          float hv = (a / (1.f + __expf(-a))) * b;   // silu(a)*b
          h[(size_t)(seg+m)*HID_DIM + n0 + nl] = f2bf(hv);
        }
      }
    }
  }
}

// ---------------- GEMM2: ybuf[pos] = w * (h @ w2 + b2), bf16 contiguous write ----------------
// 128x256 tile (8 waves 2M x 4N, per-wave 64x64): ds_read:MFMA ratio 0.5,
// LDS 48 KiB -> 3 blocks/CU.
__global__ __launch_bounds__(512,1) void gemm2_kernel(
    const u16* __restrict__ h, const u16* __restrict__ w2t, const float* __restrict__ b2,
    const float* __restrict__ token_w,
    const int* __restrict__ offsets, const int* __restrict__ counts, const int* __restrict__ pad_off,
    u16* __restrict__ ybuf)
{
  int row0 = blockIdx.y * 128;
  if (row0 >= pad_off[E_NUM]) return;
  int e = 0;
  #pragma unroll
  for (int k=1;k<E_NUM;k++) if (row0 >= pad_off[k]) e = k;
  int m0  = row0 - pad_off[e];
  int Ne  = counts[e];
  int seg = offsets[e];
  int n0  = blockIdx.x * 256;

  __shared__ u16 lA[128*64];   // 16 KiB
  __shared__ u16 lB[256*64];   // 32 KiB
  int tid=threadIdx.x, wid=tid>>6, lane=tid&63, wr=wid>>2, wc=wid&3;

  const int srcsw = (((lane&7) ^ ((lane>>3)&7))) * 8;

  size_t gA[2], gB[4];
  #pragma unroll
  for (int i=0;i<2;i++){
    int r  = wid*16 + i*8 + (lane>>3);
    int rr = m0 + r; if (rr > Ne-1) rr = Ne-1;
    gA[i] = (size_t)(seg + rr)*HID_DIM + srcsw;
  }
  #pragma unroll
  for (int i=0;i<4;i++){
    int n  = n0 + i*64 + wid*8 + (lane>>3);
    gB[i] = ((size_t)e*C_DIM + n) * HID_DIM + srcsw;
  }

  f32x4 acc[4][4];
  #pragma unroll
  for (int a=0;a<4;a++)
    #pragma unroll
    for (int b=0;b<4;b++) acc[a][b] = (f32x4){0.f,0.f,0.f,0.f};

  for (int k0=0; k0<HID_DIM; k0+=64){
    #pragma unroll
    for (int i=0;i<2;i++)
      async_copy16(h   + gA[i] + k0, &lA[(wid*16 + i*8)*64]);
    #pragma unroll
    for (int i=0;i<4;i++)
      async_copy16(w2t + gB[i] + k0, &lB[(i*64 + wid*8)*64]);
    __syncthreads();
    #pragma unroll
    for (int ks=0; ks<2; ks++){
      int kkS = ((ks*4 + (lane>>4)) ^ (lane&7)) * 8;
      bf16x8 af[4], bf[4];
      #pragma unroll
      for (int mi=0;mi<4;mi++) af[mi] = *(const bf16x8*)&lA[(wr*64+mi*16+(lane&15))*64 + kkS];
      #pragma unroll
      for (int nj=0;nj<4;nj++) bf[nj] = *(const bf16x8*)&lB[(wc*64+nj*16+(lane&15))*64 + kkS];
      #pragma unroll
      for (int mi=0;mi<4;mi++)
        #pragma unroll
        for (int nj=0;nj<4;nj++)
          acc[mi][nj] = __builtin_amdgcn_mfma_f32_16x16x32_bf16(af[mi], bf[nj], acc[mi][nj], 0,0,0);
    }
    __syncthreads();
  }

  const float* b2p = b2 + (size_t)e*C_DIM + n0;
  #pragma unroll
  for (int mi=0;mi<4;mi++){
    #pragma unroll
    for (int r=0;r<4;r++){
      int ml = wr*64 + mi*16 + (lane>>4)*4 + r;
      int m  = m0 + ml;
      if (m < Ne){
        float w = token_w[seg+m];
        #pragma unroll
        for (int nj=0;nj<4;nj++){
          int nl = wc*64 + nj*16 + (lane&15);
          ybuf[(size_t)(seg+m)*C_DIM + n0 + nl] = f2bf((acc[mi][nj][r] + b2p[nl]) * w);
        }
      }
    }
  }
}

// ---------------- combine: y[t] = ybuf[p0] + ybuf[p1] (bf16 in, fp32 out) ----------------
__global__ __launch_bounds__(256) void combine_kernel(
    const u16* __restrict__ ybuf, const int* __restrict__ pos_of_slot, float* __restrict__ y)
{
  int t = blockIdx.x;
  int p0 = pos_of_slot[t*2+0], p1 = pos_of_slot[t*2+1];
  int c = threadIdx.x;
  ushort4 a = ((const ushort4*)(ybuf + (size_t)p0*C_DIM))[c];
  ushort4 b = ((const ushort4*)(ybuf + (size_t)p1*C_DIM))[c];
  float4 o = make_float4(bf2f(a.x)+bf2f(b.x), bf2f(a.y)+bf2f(b.y),
                         bf2f(a.z)+bf2f(b.z), bf2f(a.w)+bf2f(b.w));
  ((float4*)(y + (size_t)t*C_DIM))[c] = o;
}

// ---------------- host ----------------
extern "C" void kernel_launch(void* const* d_in, const int* in_sizes, int n_in,
                              void* d_out, int out_size, void* d_ws, size_t ws_size,
                              hipStream_t stream)
{
  const float* x    = (const float*)d_in[0];
  const float* wg_w = (const float*)d_in[1];
  const float* wg_b = (const float*)d_in[2];
  const float* w1   = (const float*)d_in[3];
  const float* b1   = (const float*)d_in[4];
  const float* w3   = (const float*)d_in[5];
  const float* b3   = (const float*)d_in[6];
  const float* w2   = (const float*)d_in[7];
  const float* b2   = (const float*)d_in[8];

  float* y   = (float*)d_out;                  // S*C
  float* aux = y + (size_t)S_TOK*C_DIM;        // 1 scalar

  char* ws = (char*)d_ws;
  size_t off = 0;
  auto alloc = [&](size_t bytes) -> void* {
    void* p = ws + off;
    off += (bytes + 255) & ~(size_t)255;
    return p;
  };
  u16*  xb        = (u16*)  alloc((size_t)S_TOK*C_DIM*2);
  u16*  w1t       = (u16*)  alloc((size_t)E_NUM*HID_DIM*C_DIM*2);   // dead after gemm1
  u16*  w3t       = (u16*)  alloc((size_t)E_NUM*HID_DIM*C_DIM*2);
  u16*  w2t       = (u16*)  alloc((size_t)E_NUM*C_DIM*HID_DIM*2);
  u16*  h         = (u16*)  alloc((size_t)S_TOK*2*HID_DIM*2);
  int*  token_list= (int*)  alloc((size_t)S_TOK*2*4);
  float* token_w  = (float*)alloc((size_t)S_TOK*2*4);
  int*  top_idx   = (int*)  alloc((size_t)S_TOK*2*4);
  float* top_val  = (float*)alloc((size_t)S_TOK*2*4);
  int*  pos_of_slot=(int*)  alloc((size_t)S_TOK*2*4);
  char* stats     = (char*) alloc(4096);
  float* imp_sum  = (float*)(stats);
  int*   cnt1     = (int*)  (stats + 64);
  int*   counts   = (int*)  (stats + 128);
  int*   offsets  = (int*)  (stats + 192);
  int*   cursor   = (int*)  (stats + 256);
  int*   pad_off  = (int*)  (stats + 320);     // E_NUM+1 ints
  // ybuf (S*2 x C bf16 = 32 MiB) aliases w1t (64 MiB): dead after gemm1, stream-ordered.
  u16* ybuf = (u16*)w1t;
  (void)in_sizes; (void)n_in; (void)out_size; (void)ws_size;

  hipMemsetAsync(stats, 0, 512, stream);

  // w1 & w3 transposes merged into one launch (same shape); w2 separate.
  transpose2_kernel<<<dim3(HID_DIM/128, C_DIM/64, 2*E_NUM), 256, 0, stream>>>(
      w1, w3, w1t, w3t, C_DIM, HID_DIM);
  transpose2_kernel<<<dim3(C_DIM/128, HID_DIM/64, E_NUM), 256, 0, stream>>>(
      w2, w2, w2t, w2t, HID_DIM, C_DIM);

  gate_kernel<<<S_TOK/4, 256, 0, stream>>>(x, wg_w, wg_b, xb, top_idx, top_val, imp_sum, cnt1, counts);
  scan_kernel<<<1, 64, 0, stream>>>(counts, offsets, cursor, pad_off, imp_sum, cnt1, aux);
  scatter_kernel<<<S_TOK/256, 256, 0, stream>>>(top_idx, top_val, cursor, token_list, token_w, pos_of_slot);

  // padded-offset compact grids: sum(ceil(Ne/128)) <= 136 m-blocks total
  gemm1_kernel<<<dim3(HID_DIM/128, 136), 512, 0, stream>>>(
      xb, w1t, w3t, b1, b3, token_list, offsets, counts, pad_off, h);
  gemm2_kernel<<<dim3(C_DIM/256, 136), 512, 0, stream>>>(
      h, w2t, b2, token_w, offsets, counts, pad_off, ybuf);
  combine_kernel<<<S_TOK, 256, 0, stream>>>(ybuf, pos_of_slot, y);
}